// Round 2
// baseline (2751.586 us; speedup 1.0000x reference)
//
#include <hip/hip_runtime.h>

#define N_NODES 50000
#define N_EDGES 600000
#define N_RELS  19
#define D_IN    128
#define D_HID   64
#define D_OUT   2

// W1 [R,128,64] -> W1T [R,64,128]; loop1 [128,64] -> loop1T [64,128]
__global__ void k_transpose(const float* __restrict__ W1, const float* __restrict__ loop1,
                            float* __restrict__ W1T, float* __restrict__ loop1T){
  int idx = blockIdx.x * 256 + threadIdx.x;
  const int TOT1 = N_RELS * D_HID * D_IN;
  if (idx < TOT1) {
    int r = idx / (D_HID * D_IN);
    int t = idx % (D_HID * D_IN);
    int j = t / D_IN, d = t % D_IN;
    W1T[idx] = W1[(r * D_IN + d) * D_HID + j];
  } else {
    int k = idx - TOT1;
    if (k < D_HID * D_IN) {
      int j = k / D_IN, d = k % D_IN;
      loop1T[k] = loop1[d * D_HID + j];
    }
  }
}

// agg1[n,j] = feat[n,:] @ loop1[:,j] + b1[j]   (wave per node, lane = j)
__global__ void k_selfloop1(const float* __restrict__ feat, const float* __restrict__ loop1T,
                            const float* __restrict__ b1, float* __restrict__ agg1){
  __shared__ __align__(16) float srow[4][D_IN];
  int wave = threadIdx.x >> 6, lane = threadIdx.x & 63;
  int n = blockIdx.x * 4 + wave;
  ((float2*)srow[wave])[lane] = ((const float2*)(feat + n * D_IN))[lane];
  __syncthreads();
  const float* w = loop1T + lane * D_IN;
  float acc = b1[lane];
  #pragma unroll
  for (int p = 0; p < D_IN; p += 4) {
    float4 f4 = *(const float4*)&srow[wave][p];
    float4 w4 = *(const float4*)(w + p);
    acc = fmaf(f4.x, w4.x, acc);
    acc = fmaf(f4.y, w4.y, acc);
    acc = fmaf(f4.z, w4.z, acc);
    acc = fmaf(f4.w, w4.w, acc);
  }
  agg1[n * D_HID + lane] = acc;
}

// per edge: agg1[dst,j] += feat[src,:] @ W1[etype,:,j]   (wave per edge, lane = j)
__global__ void k_edge1(const float* __restrict__ feat, const float* __restrict__ W1T,
                        const int* __restrict__ src, const int* __restrict__ dst,
                        const int* __restrict__ et, float* __restrict__ agg1){
  __shared__ __align__(16) float srow[4][D_IN];
  int wave = threadIdx.x >> 6, lane = threadIdx.x & 63;
  int gw = blockIdx.x * 4 + wave;
  int nw = gridDim.x * 4;
  int iters = (N_EDGES + nw - 1) / nw;   // uniform trip count -> __syncthreads legal
  for (int it = 0; it < iters; ++it) {
    int e = it * nw + gw;
    bool valid = e < N_EDGES;
    int s = 0, dn = 0, r = 0;
    if (valid) {
      s = src[e]; dn = dst[e]; r = et[e];
      ((float2*)srow[wave])[lane] = ((const float2*)(feat + s * D_IN))[lane];
    }
    __syncthreads();
    if (valid) {
      const float* w = W1T + (r * D_HID + lane) * D_IN;
      float acc = 0.f;
      #pragma unroll
      for (int p = 0; p < D_IN; p += 4) {
        float4 f4 = *(const float4*)&srow[wave][p];
        float4 w4 = *(const float4*)(w + p);
        acc = fmaf(f4.x, w4.x, acc);
        acc = fmaf(f4.y, w4.y, acc);
        acc = fmaf(f4.z, w4.z, acc);
        acc = fmaf(f4.w, w4.w, acc);
      }
      atomicAdd(&agg1[dn * D_HID + lane], acc);
    }
    __syncthreads();
  }
}

// h1 = relu(agg1) in-place; out[n,k] = h1[n,:] @ loop2[:,k] + b2[k]
__global__ void k_relu_self2(float* __restrict__ agg1, const float* __restrict__ loop2,
                             const float* __restrict__ b2, float* __restrict__ out){
  int wave = threadIdx.x >> 6, lane = threadIdx.x & 63;
  int n = blockIdx.x * 4 + wave;
  float v = agg1[n * D_HID + lane];
  v = v > 0.f ? v : 0.f;
  agg1[n * D_HID + lane] = v;          // h1 in place
  float2 lw = ((const float2*)loop2)[lane];   // loop2[d][0..1]
  float p0 = v * lw.x;
  float p1 = v * lw.y;
  for (int off = 32; off; off >>= 1) {
    p0 += __shfl_down(p0, off);
    p1 += __shfl_down(p1, off);
  }
  if (lane == 0) {
    out[n * 2]     = p0 + b2[0];
    out[n * 2 + 1] = p1 + b2[1];
  }
}

// per edge: out[dst,k] += h1[src,:] @ W2[etype,:,k]   (wave per edge, lane = d)
__global__ void k_edge2(const float* __restrict__ h1, const float* __restrict__ W2,
                        const int* __restrict__ src, const int* __restrict__ dst,
                        const int* __restrict__ et, float* __restrict__ out){
  int lane = threadIdx.x & 63;
  int gw = blockIdx.x * 4 + (threadIdx.x >> 6);
  int nw = gridDim.x * 4;
  for (int e = gw; e < N_EDGES; e += nw) {
    int s = src[e], dn = dst[e], r = et[e];
    float h = h1[s * D_HID + lane];
    float2 w2 = ((const float2*)W2)[r * D_HID + lane];  // W2[r][d][0..1]
    float p0 = h * w2.x;
    float p1 = h * w2.y;
    for (int off = 32; off; off >>= 1) {
      p0 += __shfl_down(p0, off);
      p1 += __shfl_down(p1, off);
    }
    if (lane == 0) {
      atomicAdd(&out[dn * 2],     p0);
      atomicAdd(&out[dn * 2 + 1], p1);
    }
  }
}

extern "C" void kernel_launch(void* const* d_in, const int* in_sizes, int n_in,
                              void* d_out, int out_size, void* d_ws, size_t ws_size,
                              hipStream_t stream){
  const float* feat  = (const float*)d_in[0];
  const float* W1    = (const float*)d_in[1];
  const float* loop1 = (const float*)d_in[2];
  const float* b1    = (const float*)d_in[3];
  const float* W2    = (const float*)d_in[4];
  const float* loop2 = (const float*)d_in[5];
  const float* b2    = (const float*)d_in[6];
  const int* src     = (const int*)d_in[7];
  const int* dst     = (const int*)d_in[8];
  const int* et      = (const int*)d_in[9];
  float* out = (float*)d_out;

  // workspace layout (16B-aligned):
  char* w = (char*)d_ws;
  float* W1T    = (float*)(w);             // 19*64*128*4 = 622592 B
  float* loop1T = (float*)(w + 622592);    // 64*128*4    =  32768 B
  float* agg1   = (float*)(w + 655360);    // 50000*64*4  = 12.8 MB (h1 in place after relu)
                                           // total ~13.5 MB

  k_transpose <<<640,         256, 0, stream>>>(W1, loop1, W1T, loop1T);
  k_selfloop1 <<<N_NODES / 4, 256, 0, stream>>>(feat, loop1T, b1, agg1);
  k_edge1     <<<2048,        256, 0, stream>>>(feat, W1T, src, dst, et, agg1);
  k_relu_self2<<<N_NODES / 4, 256, 0, stream>>>(agg1, loop2, b2, out);
  k_edge2     <<<2048,        256, 0, stream>>>(agg1, W2, src, dst, et, out);
}

// Round 3
// 500.657 us; speedup vs baseline: 5.4959x; 5.4959x over previous
//
#include <hip/hip_runtime.h>

#define N_NODES 50000
#define N_EDGES 600000
#define N_RELS  19
#define D_IN    128
#define D_HID   64
#define D_OUT   2

typedef unsigned short u16;
typedef unsigned int   u32;
typedef __attribute__((ext_vector_type(8))) short sfrag;   // 8 bf16 (4 VGPRs)
typedef __attribute__((ext_vector_type(4))) float f32x4;   // 4 fp32 acc

__device__ __forceinline__ u16 f2bf(float f){
  union { float f; u32 i; } v; v.f = f;
  u32 r = v.i + 0x7fffu + ((v.i >> 16) & 1u);  // RNE
  return (u16)(r >> 16);
}

// Pre-transform weights:
//  W1Tb [19][64][128] bf16  <- W1 [19][128][64] fp32   (B^T layout, contiguous-K)
//  W2Tb [19][16][64]  bf16  <- W2 [19][64][2]   fp32   (cols 2..15 zero)
//  loop1T [64][128]   fp32  <- loop1 [128][64]
__global__ void k_prep(const float* __restrict__ W1, const float* __restrict__ loop1,
                       const float* __restrict__ W2,
                       u16* __restrict__ W1Tb, float* __restrict__ loop1T,
                       u16* __restrict__ W2Tb){
  int idx = blockIdx.x * 256 + threadIdx.x;
  const int T1 = N_RELS * D_HID * D_IN;        // 155648
  const int T2 = T1 + N_RELS * 16 * D_HID;     // +19456
  const int T3 = T2 + D_HID * D_IN;            // +8192
  if (idx < T1) {
    int r = idx / (D_HID * D_IN);
    int t = idx - r * (D_HID * D_IN);
    int j = t >> 7, d = t & 127;
    W1Tb[idx] = f2bf(W1[(r * D_IN + d) * D_HID + j]);
  } else if (idx < T2) {
    int k2 = idx - T1;
    int r = k2 / (16 * D_HID);
    int t = k2 - r * (16 * D_HID);
    int n = t >> 6, k = t & 63;
    W2Tb[k2] = (n < D_OUT) ? f2bf(W2[(r * D_HID + k) * D_OUT + n]) : (u16)0;
  } else if (idx < T3) {
    int k2 = idx - T2;
    int j = k2 >> 7, d = k2 & 127;
    loop1T[k2] = loop1[d * D_HID + j];
  }
}

// ---- counting sort of edges by relation ----
__global__ void k_zero(int* __restrict__ hist){
  if (threadIdx.x < N_RELS) hist[threadIdx.x] = 0;
}

__global__ __launch_bounds__(256) void k_hist(const int* __restrict__ et, int* __restrict__ hist){
  __shared__ int lh[N_RELS];
  int tid = threadIdx.x;
  if (tid < N_RELS) lh[tid] = 0;
  __syncthreads();
  int e = blockIdx.x * 256 + tid;
  if (e < N_EDGES) atomicAdd(&lh[et[e]], 1);
  __syncthreads();
  if (tid < N_RELS && lh[tid]) atomicAdd(&hist[tid], lh[tid]);
}

__global__ void k_scan(const int* __restrict__ hist, int* __restrict__ offs,
                       int* __restrict__ toff, int* __restrict__ cursor){
  if (threadIdx.x == 0) {
    int acc = 0, tacc = 0;
    offs[0] = 0; toff[0] = 0;
    for (int r = 0; r < N_RELS; ++r) {
      cursor[r] = acc;
      int c = hist[r];
      acc += c;               offs[r + 1] = acc;
      tacc += (c + 63) >> 6;  toff[r + 1] = tacc;
    }
  }
}

__global__ __launch_bounds__(256) void k_scatter(const int* __restrict__ et,
                                                 int* __restrict__ cursor,
                                                 int* __restrict__ perm){
  __shared__ int lh[N_RELS], base[N_RELS];
  int tid = threadIdx.x;
  if (tid < N_RELS) lh[tid] = 0;
  __syncthreads();
  int e = blockIdx.x * 256 + tid;
  int r = 0, my = 0;
  bool valid = e < N_EDGES;
  if (valid) { r = et[e]; my = atomicAdd(&lh[r], 1); }
  __syncthreads();
  if (tid < N_RELS && lh[tid]) base[tid] = atomicAdd(&cursor[tid], lh[tid]);
  __syncthreads();
  if (valid) perm[base[r] + my] = e;
}

// agg1[n,j] = feat[n,:] @ loop1[:,j] + b1[j]   (wave per node, lane = j) -- full init of agg1
__global__ __launch_bounds__(256) void k_selfloop1(const float* __restrict__ feat,
                                                   const float* __restrict__ loop1T,
                                                   const float* __restrict__ b1,
                                                   float* __restrict__ agg1){
  __shared__ __align__(16) float srow[4][D_IN];
  int wave = threadIdx.x >> 6, lane = threadIdx.x & 63;
  int n = blockIdx.x * 4 + wave;
  ((float2*)srow[wave])[lane] = ((const float2*)(feat + n * D_IN))[lane];
  __syncthreads();
  const float* w = loop1T + lane * D_IN;
  float acc = b1[lane];
  #pragma unroll
  for (int p = 0; p < D_IN; p += 4) {
    float4 f4 = *(const float4*)&srow[wave][p];
    float4 w4 = *(const float4*)(w + p);
    acc = fmaf(f4.x, w4.x, acc);
    acc = fmaf(f4.y, w4.y, acc);
    acc = fmaf(f4.z, w4.z, acc);
    acc = fmaf(f4.w, w4.w, acc);
  }
  agg1[n * D_HID + lane] = acc;
}

// Layer-1 edge messages: tile = 64 edges (one relation) x 64 cols, K=128, bf16 MFMA.
__global__ __launch_bounds__(256) void k_edge1_mfma(
    const float* __restrict__ feat, const u16* __restrict__ W1Tb,
    const int* __restrict__ src, const int* __restrict__ dst,
    const int* __restrict__ perm, const int* __restrict__ offs,
    const int* __restrict__ toff, float* __restrict__ agg1){
  __shared__ __align__(16) u16 Als[64][136];   // 64 edge rows x 128 K (+8 pad)
  __shared__ __align__(16) u16 Bls[64][136];   // 64 cols     x 128 K (+8 pad)
  __shared__ int dstIds[64];
  __shared__ int sMeta[3];   // rel, tileStart, vcount
  int tid = threadIdx.x;
  if (tid == 0) {
    int b = blockIdx.x, r = 0, vc = 0, ts = 0;
    if (b < toff[N_RELS]) {
      while (b >= toff[r + 1]) ++r;
      ts = offs[r] + ((b - toff[r]) << 6);
      vc = offs[r + 1] - ts; if (vc > 64) vc = 64;
    }
    sMeta[0] = r; sMeta[1] = ts; sMeta[2] = vc;
  }
  __syncthreads();
  int vcount = sMeta[2];
  if (vcount == 0) return;                       // uniform exit
  int rel = sMeta[0], tileStart = sMeta[1];

  { // load B tile: W1Tb[rel], 64 rows x 128 bf16 (16 KB)
    int j = tid >> 2, seg = tid & 3;
    const uint4* g = (const uint4*)(W1Tb + (rel * 64 + j) * 128) + seg * 4;
    uint4* d = (uint4*)&Bls[j][seg * 32];
    d[0] = g[0]; d[1] = g[1]; d[2] = g[2]; d[3] = g[3];
  }
  { // gather A tile: feat rows fp32 -> bf16
    int i = tid >> 2, seg = tid & 3;
    if (i < vcount) {
      int e = perm[tileStart + i];
      if (seg == 0) dstIds[i] = dst[e];
      const float4* fp = (const float4*)(feat + src[e] * D_IN) + seg * 8;
      #pragma unroll
      for (int q = 0; q < 4; ++q) {
        float4 x = fp[2 * q], y = fp[2 * q + 1];
        u32 p0 = (u32)f2bf(x.x) | ((u32)f2bf(x.y) << 16);
        u32 p1 = (u32)f2bf(x.z) | ((u32)f2bf(x.w) << 16);
        u32 p2 = (u32)f2bf(y.x) | ((u32)f2bf(y.y) << 16);
        u32 p3 = (u32)f2bf(y.z) | ((u32)f2bf(y.w) << 16);
        *(uint4*)&Als[i][seg * 32 + q * 8] = make_uint4(p0, p1, p2, p3);
      }
    } else {
      if (seg == 0) dstIds[i] = -1;
      uint4 z = make_uint4(0, 0, 0, 0);
      #pragma unroll
      for (int q = 0; q < 4; ++q) *(uint4*)&Als[i][seg * 32 + q * 8] = z;
    }
  }
  __syncthreads();

  int w = tid >> 6, lane = tid & 63;
  int r16 = lane & 15, c4 = lane >> 4;
  // fragment mapping (m89/m91-verified): x[j] <-> [lane&15][(lane>>4)*8 + j]
  sfrag aF[4];
  #pragma unroll
  for (int kk = 0; kk < 4; ++kk)
    aF[kk] = *(const sfrag*)&Als[w * 16 + r16][kk * 32 + c4 * 8];
  #pragma unroll
  for (int ct = 0; ct < 4; ++ct) {
    f32x4 acc = {0.f, 0.f, 0.f, 0.f};
    #pragma unroll
    for (int kk = 0; kk < 4; ++kk) {
      sfrag bF = *(const sfrag*)&Bls[ct * 16 + r16][kk * 32 + c4 * 8];
      acc = __builtin_amdgcn_mfma_f32_16x16x32_bf16(aF[kk], bF, acc, 0, 0, 0);
    }
    int col = ct * 16 + r16;
    #pragma unroll
    for (int reg = 0; reg < 4; ++reg) {
      int row = w * 16 + c4 * 4 + reg;   // D: col=lane&15, row=(lane>>4)*4+reg
      int dn = dstIds[row];
      if (dn >= 0) atomicAdd(&agg1[dn * D_HID + col], acc[reg]);
    }
  }
}

// h1 = relu(agg1) written back IN PLACE as bf16 (lockstep-safe: per-lane load precedes store);
// out[n,k] = relu(agg1[n,:]) @ loop2[:,k] + b2[k]  -- full init of out
__global__ __launch_bounds__(256) void k_relu_self2(float* __restrict__ agg1,
                                                     const float* __restrict__ loop2,
                                                     const float* __restrict__ b2,
                                                     float* __restrict__ out){
  int wave = threadIdx.x >> 6, lane = threadIdx.x & 63;
  int n = blockIdx.x * 4 + wave;
  float v = agg1[n * D_HID + lane];
  v = v > 0.f ? v : 0.f;
  ((u16*)agg1)[n * D_HID + lane] = f2bf(v);    // h1b alias
  float2 lw = ((const float2*)loop2)[lane];
  float p0 = v * lw.x, p1 = v * lw.y;
  for (int off = 32; off; off >>= 1) {
    p0 += __shfl_down(p0, off);
    p1 += __shfl_down(p1, off);
  }
  if (lane == 0) {
    out[n * 2]     = p0 + b2[0];
    out[n * 2 + 1] = p1 + b2[1];
  }
}

// Layer-2 edge messages: tile = 64 edges x 16 cols (2 valid), K=64, bf16 MFMA.
__global__ __launch_bounds__(256) void k_edge2_mfma(
    const u16* __restrict__ h1b, const u16* __restrict__ W2Tb,
    const int* __restrict__ src, const int* __restrict__ dst,
    const int* __restrict__ perm, const int* __restrict__ offs,
    const int* __restrict__ toff, float* __restrict__ out){
  __shared__ __align__(16) u16 Als[64][72];
  __shared__ __align__(16) u16 Bls[16][72];
  __shared__ int dstIds[64];
  __shared__ int sMeta[3];
  int tid = threadIdx.x;
  if (tid == 0) {
    int b = blockIdx.x, r = 0, vc = 0, ts = 0;
    if (b < toff[N_RELS]) {
      while (b >= toff[r + 1]) ++r;
      ts = offs[r] + ((b - toff[r]) << 6);
      vc = offs[r + 1] - ts; if (vc > 64) vc = 64;
    }
    sMeta[0] = r; sMeta[1] = ts; sMeta[2] = vc;
  }
  __syncthreads();
  int vcount = sMeta[2];
  if (vcount == 0) return;
  int rel = sMeta[0], tileStart = sMeta[1];

  if (tid < 128) {   // B tile: 16 x 64 bf16 = 128 uint4
    int n = tid >> 3, q = tid & 7;
    ((uint4*)&Bls[n][0])[q] = ((const uint4*)(W2Tb + rel * 16 * 64))[tid];
  }
  { // gather A: h1b rows (already bf16)
    int i = tid >> 2, seg = tid & 3;
    if (i < vcount) {
      int e = perm[tileStart + i];
      if (seg == 0) dstIds[i] = dst[e];
      const uint4* g = (const uint4*)(h1b + src[e] * D_HID) + seg * 2;
      *(uint4*)&Als[i][seg * 16]     = g[0];
      *(uint4*)&Als[i][seg * 16 + 8] = g[1];
    } else {
      if (seg == 0) dstIds[i] = -1;
      uint4 z = make_uint4(0, 0, 0, 0);
      *(uint4*)&Als[i][seg * 16]     = z;
      *(uint4*)&Als[i][seg * 16 + 8] = z;
    }
  }
  __syncthreads();

  int w = tid >> 6, lane = tid & 63;
  int r16 = lane & 15, c4 = lane >> 4;
  f32x4 acc = {0.f, 0.f, 0.f, 0.f};
  #pragma unroll
  for (int kk = 0; kk < 2; ++kk) {
    sfrag aF = *(const sfrag*)&Als[w * 16 + r16][kk * 32 + c4 * 8];
    sfrag bF = *(const sfrag*)&Bls[r16][kk * 32 + c4 * 8];
    acc = __builtin_amdgcn_mfma_f32_16x16x32_bf16(aF, bF, acc, 0, 0, 0);
  }
  if (r16 < D_OUT) {
    #pragma unroll
    for (int reg = 0; reg < 4; ++reg) {
      int row = w * 16 + c4 * 4 + reg;
      int dn = dstIds[row];
      if (dn >= 0) atomicAdd(&out[dn * D_OUT + r16], acc[reg]);
    }
  }
}

extern "C" void kernel_launch(void* const* d_in, const int* in_sizes, int n_in,
                              void* d_out, int out_size, void* d_ws, size_t ws_size,
                              hipStream_t stream){
  const float* feat  = (const float*)d_in[0];
  const float* W1    = (const float*)d_in[1];
  const float* loop1 = (const float*)d_in[2];
  const float* b1    = (const float*)d_in[3];
  const float* W2    = (const float*)d_in[4];
  const float* loop2 = (const float*)d_in[5];
  const float* b2    = (const float*)d_in[6];
  const int* src     = (const int*)d_in[7];
  const int* dst     = (const int*)d_in[8];
  const int* et      = (const int*)d_in[9];
  float* out = (float*)d_out;

  // workspace layout (16B-aligned), ~15.6 MB total
  char* w = (char*)d_ws;
  u16*   W1Tb   = (u16*)(w);                  // 311296 B
  u16*   W2Tb   = (u16*)(w + 311296);         //  38912 B
  float* loop1T = (float*)(w + 350208);       //  32768 B
  int*   hist   = (int*)(w + 382976);
  int*   cursor = (int*)(w + 383104);
  int*   offs   = (int*)(w + 383232);
  int*   toff   = (int*)(w + 383360);
  int*   perm   = (int*)(w + 383488);         // 2.4 MB
  float* agg1   = (float*)(w + 2783488);      // 12.8 MB (h1 bf16 aliased in place after relu)

  const int MAX_TILES = (N_EDGES + 63) / 64 + N_RELS;   // 9394 upper bound

  k_prep      <<<716,   256, 0, stream>>>(W1, loop1, W2, W1Tb, loop1T, W2Tb);
  k_zero      <<<1,      64, 0, stream>>>(hist);
  k_hist      <<<2344,  256, 0, stream>>>(et, hist);
  k_scan      <<<1,      64, 0, stream>>>(hist, offs, toff, cursor);
  k_scatter   <<<2344,  256, 0, stream>>>(et, cursor, perm);
  k_selfloop1 <<<N_NODES / 4, 256, 0, stream>>>(feat, loop1T, b1, agg1);
  k_edge1_mfma<<<MAX_TILES,   256, 0, stream>>>(feat, W1Tb, src, dst, perm, offs, toff, agg1);
  k_relu_self2<<<N_NODES / 4, 256, 0, stream>>>(agg1, loop2, b2, out);
  k_edge2_mfma<<<MAX_TILES,   256, 0, stream>>>((const u16*)agg1, W2Tb, src, dst, perm, offs, toff, out);
}

// Round 4
// 337.038 us; speedup vs baseline: 8.1640x; 1.4855x over previous
//
#include <hip/hip_runtime.h>

#define N_NODES 50000
#define N_EDGES 600000
#define N_RELS  19
#define D_IN    128
#define D_HID   64
#define D_OUT   2

typedef unsigned short u16;
typedef unsigned int   u32;
typedef __attribute__((ext_vector_type(8))) short sfrag;   // 8 bf16 (4 VGPRs)
typedef __attribute__((ext_vector_type(4))) float f32x4;   // 4 fp32 acc

__device__ __forceinline__ u16 f2bf(float f){
  union { float f; u32 i; } v; v.f = f;
  u32 r = v.i + 0x7fffu + ((v.i >> 16) & 1u);  // RNE
  return (u16)(r >> 16);
}

// Pre-transform weights:
//  W1Tb   [19][64][128] bf16 <- W1 [19][128][64] fp32   (B^T layout, contiguous-K)
//  W2Tb   [19][16][64]  bf16 <- W2 [19][64][2]   fp32   (cols 2..15 zero)
//  loop1Tb[64][128]     bf16 <- loop1 [128][64]  fp32   (B^T layout)
__global__ void k_prep(const float* __restrict__ W1, const float* __restrict__ loop1,
                       const float* __restrict__ W2,
                       u16* __restrict__ W1Tb, u16* __restrict__ loop1Tb,
                       u16* __restrict__ W2Tb){
  int idx = blockIdx.x * 256 + threadIdx.x;
  const int T1 = N_RELS * D_HID * D_IN;        // 155648
  const int T2 = T1 + N_RELS * 16 * D_HID;     // +19456
  const int T3 = T2 + D_HID * D_IN;            // +8192
  if (idx < T1) {
    int r = idx / (D_HID * D_IN);
    int t = idx - r * (D_HID * D_IN);
    int j = t >> 7, d = t & 127;
    W1Tb[idx] = f2bf(W1[(r * D_IN + d) * D_HID + j]);
  } else if (idx < T2) {
    int k2 = idx - T1;
    int r = k2 / (16 * D_HID);
    int t = k2 - r * (16 * D_HID);
    int n = t >> 6, k = t & 63;
    W2Tb[k2] = (n < D_OUT) ? f2bf(W2[(r * D_HID + k) * D_OUT + n]) : (u16)0;
  } else if (idx < T3) {
    int k2 = idx - T2;
    int j = k2 >> 7, d = k2 & 127;
    loop1Tb[k2] = f2bf(loop1[d * D_HID + j]);
  }
}

// ---- counting sort of edges by relation ----
__global__ void k_zero(int* __restrict__ hist){
  if (threadIdx.x < N_RELS) hist[threadIdx.x] = 0;
}

__global__ __launch_bounds__(256) void k_hist(const int* __restrict__ et, int* __restrict__ hist){
  __shared__ int lh[N_RELS];
  int tid = threadIdx.x;
  if (tid < N_RELS) lh[tid] = 0;
  __syncthreads();
  int e = blockIdx.x * 256 + tid;
  if (e < N_EDGES) atomicAdd(&lh[et[e]], 1);
  __syncthreads();
  if (tid < N_RELS && lh[tid]) atomicAdd(&hist[tid], lh[tid]);
}

__global__ void k_scan(const int* __restrict__ hist, int* __restrict__ offs,
                       int* __restrict__ toff, int* __restrict__ cursor){
  if (threadIdx.x == 0) {
    int acc = 0, tacc = 0;
    offs[0] = 0; toff[0] = 0;
    for (int r = 0; r < N_RELS; ++r) {
      cursor[r] = acc;
      int c = hist[r];
      acc += c;               offs[r + 1] = acc;
      tacc += (c + 63) >> 6;  toff[r + 1] = tacc;
    }
  }
}

__global__ __launch_bounds__(256) void k_scatter(const int* __restrict__ et,
                                                 int* __restrict__ cursor,
                                                 int* __restrict__ perm){
  __shared__ int lh[N_RELS], base[N_RELS];
  int tid = threadIdx.x;
  if (tid < N_RELS) lh[tid] = 0;
  __syncthreads();
  int e = blockIdx.x * 256 + tid;
  int r = 0, my = 0;
  bool valid = e < N_EDGES;
  if (valid) { r = et[e]; my = atomicAdd(&lh[r], 1); }
  __syncthreads();
  if (tid < N_RELS && lh[tid]) base[tid] = atomicAdd(&cursor[tid], lh[tid]);
  __syncthreads();
  if (valid) perm[base[r] + my] = e;
}

// Self-loop layer 1 as dense MFMA GEMM: agg1[64-node tile] = feat @ loop1 + b1.
// Full init of agg1 (must run before k_edge1_mfma's atomics).
__global__ __launch_bounds__(256) void k_selfloop1_mfma(
    const float* __restrict__ feat, const u16* __restrict__ loop1Tb,
    const float* __restrict__ b1, float* __restrict__ agg1){
  __shared__ __align__(16) u16 Als[64][136];
  __shared__ __align__(16) u16 Bls[64][136];
  int tid = threadIdx.x;
  int base = blockIdx.x * 64;
  { // B tile: loop1Tb, 64 x 128 bf16 (16 KB)
    int j = tid >> 2, seg = tid & 3;
    const uint4* g = (const uint4*)(loop1Tb + j * 128) + seg * 4;
    uint4* d = (uint4*)&Bls[j][seg * 32];
    d[0] = g[0]; d[1] = g[1]; d[2] = g[2]; d[3] = g[3];
  }
  { // A tile: feat rows fp32 -> bf16 (coalesced, no gather)
    int i = tid >> 2, seg = tid & 3;
    int n = base + i; if (n >= N_NODES) n = 0;   // clamp; stores skipped below
    const float4* fp = (const float4*)(feat + n * D_IN) + seg * 8;
    #pragma unroll
    for (int q = 0; q < 4; ++q) {
      float4 x = fp[2 * q], y = fp[2 * q + 1];
      u32 p0 = (u32)f2bf(x.x) | ((u32)f2bf(x.y) << 16);
      u32 p1 = (u32)f2bf(x.z) | ((u32)f2bf(x.w) << 16);
      u32 p2 = (u32)f2bf(y.x) | ((u32)f2bf(y.y) << 16);
      u32 p3 = (u32)f2bf(y.z) | ((u32)f2bf(y.w) << 16);
      *(uint4*)&Als[i][seg * 32 + q * 8] = make_uint4(p0, p1, p2, p3);
    }
  }
  __syncthreads();

  int w = tid >> 6, lane = tid & 63;
  int r16 = lane & 15, c4 = lane >> 4;
  sfrag aF[4];
  #pragma unroll
  for (int kk = 0; kk < 4; ++kk)
    aF[kk] = *(const sfrag*)&Als[w * 16 + r16][kk * 32 + c4 * 8];
  #pragma unroll
  for (int ct = 0; ct < 4; ++ct) {
    f32x4 acc = {0.f, 0.f, 0.f, 0.f};
    #pragma unroll
    for (int kk = 0; kk < 4; ++kk) {
      sfrag bF = *(const sfrag*)&Bls[ct * 16 + r16][kk * 32 + c4 * 8];
      acc = __builtin_amdgcn_mfma_f32_16x16x32_bf16(aF[kk], bF, acc, 0, 0, 0);
    }
    int col = ct * 16 + r16;
    float bias = b1[col];
    #pragma unroll
    for (int reg = 0; reg < 4; ++reg) {
      int row = base + w * 16 + c4 * 4 + reg;   // D: col=lane&15, row=(lane>>4)*4+reg
      if (row < N_NODES) agg1[row * D_HID + col] = acc[reg] + bias;
    }
  }
}

// Layer-1 edge messages: tile = 64 edges (one relation) x 64 cols, K=128, bf16 MFMA.
__global__ __launch_bounds__(256) void k_edge1_mfma(
    const float* __restrict__ feat, const u16* __restrict__ W1Tb,
    const int* __restrict__ src, const int* __restrict__ dst,
    const int* __restrict__ perm, const int* __restrict__ offs,
    const int* __restrict__ toff, float* __restrict__ agg1){
  __shared__ __align__(16) u16 Als[64][136];
  __shared__ __align__(16) u16 Bls[64][136];
  __shared__ int dstIds[64];
  __shared__ int sMeta[3];   // rel, tileStart, vcount
  int tid = threadIdx.x;
  if (tid == 0) {
    int b = blockIdx.x, r = 0, vc = 0, ts = 0;
    if (b < toff[N_RELS]) {
      while (b >= toff[r + 1]) ++r;
      ts = offs[r] + ((b - toff[r]) << 6);
      vc = offs[r + 1] - ts; if (vc > 64) vc = 64;
    }
    sMeta[0] = r; sMeta[1] = ts; sMeta[2] = vc;
  }
  __syncthreads();
  int vcount = sMeta[2];
  if (vcount == 0) return;                       // uniform exit
  int rel = sMeta[0], tileStart = sMeta[1];

  { // load B tile: W1Tb[rel], 64 rows x 128 bf16 (16 KB)
    int j = tid >> 2, seg = tid & 3;
    const uint4* g = (const uint4*)(W1Tb + (rel * 64 + j) * 128) + seg * 4;
    uint4* d = (uint4*)&Bls[j][seg * 32];
    d[0] = g[0]; d[1] = g[1]; d[2] = g[2]; d[3] = g[3];
  }
  { // gather A tile: feat rows fp32 -> bf16
    int i = tid >> 2, seg = tid & 3;
    if (i < vcount) {
      int e = perm[tileStart + i];
      if (seg == 0) dstIds[i] = dst[e];
      const float4* fp = (const float4*)(feat + src[e] * D_IN) + seg * 8;
      #pragma unroll
      for (int q = 0; q < 4; ++q) {
        float4 x = fp[2 * q], y = fp[2 * q + 1];
        u32 p0 = (u32)f2bf(x.x) | ((u32)f2bf(x.y) << 16);
        u32 p1 = (u32)f2bf(x.z) | ((u32)f2bf(x.w) << 16);
        u32 p2 = (u32)f2bf(y.x) | ((u32)f2bf(y.y) << 16);
        u32 p3 = (u32)f2bf(y.z) | ((u32)f2bf(y.w) << 16);
        *(uint4*)&Als[i][seg * 32 + q * 8] = make_uint4(p0, p1, p2, p3);
      }
    } else {
      if (seg == 0) dstIds[i] = -1;
      uint4 z = make_uint4(0, 0, 0, 0);
      #pragma unroll
      for (int q = 0; q < 4; ++q) *(uint4*)&Als[i][seg * 32 + q * 8] = z;
    }
  }
  __syncthreads();

  int w = tid >> 6, lane = tid & 63;
  int r16 = lane & 15, c4 = lane >> 4;
  // fragment mapping (m89/m91-verified): x[j] <-> [lane&15][(lane>>4)*8 + j]
  sfrag aF[4];
  #pragma unroll
  for (int kk = 0; kk < 4; ++kk)
    aF[kk] = *(const sfrag*)&Als[w * 16 + r16][kk * 32 + c4 * 8];
  #pragma unroll
  for (int ct = 0; ct < 4; ++ct) {
    f32x4 acc = {0.f, 0.f, 0.f, 0.f};
    #pragma unroll
    for (int kk = 0; kk < 4; ++kk) {
      sfrag bF = *(const sfrag*)&Bls[ct * 16 + r16][kk * 32 + c4 * 8];
      acc = __builtin_amdgcn_mfma_f32_16x16x32_bf16(aF[kk], bF, acc, 0, 0, 0);
    }
    int col = ct * 16 + r16;
    #pragma unroll
    for (int reg = 0; reg < 4; ++reg) {
      int row = w * 16 + c4 * 4 + reg;   // D: col=lane&15, row=(lane>>4)*4+reg
      int dn = dstIds[row];
      if (dn >= 0) atomicAdd(&agg1[dn * D_HID + col], acc[reg]);
    }
  }
}

// h1 = relu(agg1) written back IN PLACE as bf16 (lockstep-safe: per-lane load precedes store);
// out[n,k] = relu(agg1[n,:]) @ loop2[:,k] + b2[k]  -- full init of out
__global__ __launch_bounds__(256) void k_relu_self2(float* __restrict__ agg1,
                                                     const float* __restrict__ loop2,
                                                     const float* __restrict__ b2,
                                                     float* __restrict__ out){
  int wave = threadIdx.x >> 6, lane = threadIdx.x & 63;
  int n = blockIdx.x * 4 + wave;
  float v = agg1[n * D_HID + lane];
  v = v > 0.f ? v : 0.f;
  ((u16*)agg1)[n * D_HID + lane] = f2bf(v);    // h1b alias
  float2 lw = ((const float2*)loop2)[lane];
  float p0 = v * lw.x, p1 = v * lw.y;
  for (int off = 32; off; off >>= 1) {
    p0 += __shfl_down(p0, off);
    p1 += __shfl_down(p1, off);
  }
  if (lane == 0) {
    out[n * 2]     = p0 + b2[0];
    out[n * 2 + 1] = p1 + b2[1];
  }
}

// Layer-2 edge messages: tile = 64 edges x 16 cols (2 valid), K=64, bf16 MFMA.
__global__ __launch_bounds__(256) void k_edge2_mfma(
    const u16* __restrict__ h1b, const u16* __restrict__ W2Tb,
    const int* __restrict__ src, const int* __restrict__ dst,
    const int* __restrict__ perm, const int* __restrict__ offs,
    const int* __restrict__ toff, float* __restrict__ out){
  __shared__ __align__(16) u16 Als[64][72];
  __shared__ __align__(16) u16 Bls[16][72];
  __shared__ int dstIds[64];
  __shared__ int sMeta[3];
  int tid = threadIdx.x;
  if (tid == 0) {
    int b = blockIdx.x, r = 0, vc = 0, ts = 0;
    if (b < toff[N_RELS]) {
      while (b >= toff[r + 1]) ++r;
      ts = offs[r] + ((b - toff[r]) << 6);
      vc = offs[r + 1] - ts; if (vc > 64) vc = 64;
    }
    sMeta[0] = r; sMeta[1] = ts; sMeta[2] = vc;
  }
  __syncthreads();
  int vcount = sMeta[2];
  if (vcount == 0) return;
  int rel = sMeta[0], tileStart = sMeta[1];

  if (tid < 128) {   // B tile: 16 x 64 bf16 = 128 uint4
    int n = tid >> 3, q = tid & 7;
    ((uint4*)&Bls[n][0])[q] = ((const uint4*)(W2Tb + rel * 16 * 64))[tid];
  }
  { // gather A: h1b rows (already bf16)
    int i = tid >> 2, seg = tid & 3;
    if (i < vcount) {
      int e = perm[tileStart + i];
      if (seg == 0) dstIds[i] = dst[e];
      const uint4* g = (const uint4*)(h1b + src[e] * D_HID) + seg * 2;
      *(uint4*)&Als[i][seg * 16]     = g[0];
      *(uint4*)&Als[i][seg * 16 + 8] = g[1];
    } else {
      if (seg == 0) dstIds[i] = -1;
      uint4 z = make_uint4(0, 0, 0, 0);
      *(uint4*)&Als[i][seg * 16]     = z;
      *(uint4*)&Als[i][seg * 16 + 8] = z;
    }
  }
  __syncthreads();

  int w = tid >> 6, lane = tid & 63;
  int r16 = lane & 15, c4 = lane >> 4;
  f32x4 acc = {0.f, 0.f, 0.f, 0.f};
  #pragma unroll
  for (int kk = 0; kk < 2; ++kk) {
    sfrag aF = *(const sfrag*)&Als[w * 16 + r16][kk * 32 + c4 * 8];
    sfrag bF = *(const sfrag*)&Bls[r16][kk * 32 + c4 * 8];
    acc = __builtin_amdgcn_mfma_f32_16x16x32_bf16(aF, bF, acc, 0, 0, 0);
  }
  if (r16 < D_OUT) {
    #pragma unroll
    for (int reg = 0; reg < 4; ++reg) {
      int row = w * 16 + c4 * 4 + reg;
      int dn = dstIds[row];
      if (dn >= 0) atomicAdd(&out[dn * D_OUT + r16], acc[reg]);
    }
  }
}

extern "C" void kernel_launch(void* const* d_in, const int* in_sizes, int n_in,
                              void* d_out, int out_size, void* d_ws, size_t ws_size,
                              hipStream_t stream){
  const float* feat  = (const float*)d_in[0];
  const float* W1    = (const float*)d_in[1];
  const float* loop1 = (const float*)d_in[2];
  const float* b1    = (const float*)d_in[3];
  const float* W2    = (const float*)d_in[4];
  const float* loop2 = (const float*)d_in[5];
  const float* b2    = (const float*)d_in[6];
  const int* src     = (const int*)d_in[7];
  const int* dst     = (const int*)d_in[8];
  const int* et      = (const int*)d_in[9];
  float* out = (float*)d_out;

  // workspace layout (16B-aligned), ~15.6 MB total
  char* w = (char*)d_ws;
  u16*   W1Tb    = (u16*)(w);                  // 311296 B
  u16*   W2Tb    = (u16*)(w + 311296);         //  38912 B
  u16*   loop1Tb = (u16*)(w + 350208);         //  16384 B (slot is 32768)
  int*   hist    = (int*)(w + 382976);
  int*   cursor  = (int*)(w + 383104);
  int*   offs    = (int*)(w + 383232);
  int*   toff    = (int*)(w + 383360);
  int*   perm    = (int*)(w + 383488);         // 2.4 MB
  float* agg1    = (float*)(w + 2783488);      // 12.8 MB (h1 bf16 aliased in place after relu)

  const int MAX_TILES = (N_EDGES + 63) / 64 + N_RELS;   // 9394 upper bound

  k_prep          <<<716,   256, 0, stream>>>(W1, loop1, W2, W1Tb, loop1Tb, W2Tb);
  k_zero          <<<1,      64, 0, stream>>>(hist);
  k_hist          <<<2344,  256, 0, stream>>>(et, hist);
  k_scan          <<<1,      64, 0, stream>>>(hist, offs, toff, cursor);
  k_scatter       <<<2344,  256, 0, stream>>>(et, cursor, perm);
  k_selfloop1_mfma<<<(N_NODES + 63) / 64, 256, 0, stream>>>(feat, loop1Tb, b1, agg1);
  k_edge1_mfma    <<<MAX_TILES,   256, 0, stream>>>(feat, W1Tb, src, dst, perm, offs, toff, agg1);
  k_relu_self2    <<<N_NODES / 4, 256, 0, stream>>>(agg1, loop2, b2, out);
  k_edge2_mfma    <<<MAX_TILES,   256, 0, stream>>>((const u16*)agg1, W2Tb, src, dst, perm, offs, toff, out);
}

// Round 5
// 336.161 us; speedup vs baseline: 8.1853x; 1.0026x over previous
//
#include <hip/hip_runtime.h>

#define N_NODES 50000
#define N_EDGES 600000
#define N_RELS  19
#define D_IN    128
#define D_HID   64
#define D_OUT   2

typedef unsigned short u16;
typedef unsigned int   u32;
typedef __attribute__((ext_vector_type(8))) short sfrag;   // 8 bf16 (4 VGPRs)
typedef __attribute__((ext_vector_type(4))) float f32x4;   // 4 fp32 acc

__device__ __forceinline__ u16 f2bf(float f){
  union { float f; u32 i; } v; v.f = f;
  u32 r = v.i + 0x7fffu + ((v.i >> 16) & 1u);  // RNE
  return (u16)(r >> 16);
}
__device__ __forceinline__ float bf2f(u16 u){
  union { u32 i; float f; } v; v.i = ((u32)u) << 16; return v.f;
}

// feat fp32 -> featb bf16 (packed u32 pairs), 3.2M u32
__global__ __launch_bounds__(256) void k_featb(const float* __restrict__ feat,
                                               u16* __restrict__ featb){
  int i = blockIdx.x * 256 + threadIdx.x;
  float2 f = ((const float2*)feat)[i];
  ((u32*)featb)[i] = (u32)f2bf(f.x) | ((u32)f2bf(f.y) << 16);
}

// Pre-transform weights:
//  W1Tb   [19][64][128] bf16 <- W1 [19][128][64] fp32   (B^T layout, contiguous-K)
//  W2Tb   [19][16][64]  bf16 <- W2 [19][64][2]   fp32   (cols 2..15 zero)
//  loop1Tb[64][128]     bf16 <- loop1 [128][64]  fp32   (B^T layout)
__global__ void k_prep(const float* __restrict__ W1, const float* __restrict__ loop1,
                       const float* __restrict__ W2,
                       u16* __restrict__ W1Tb, u16* __restrict__ loop1Tb,
                       u16* __restrict__ W2Tb){
  int idx = blockIdx.x * 256 + threadIdx.x;
  const int T1 = N_RELS * D_HID * D_IN;        // 155648
  const int T2 = T1 + N_RELS * 16 * D_HID;     // +19456
  const int T3 = T2 + D_HID * D_IN;            // +8192
  if (idx < T1) {
    int r = idx / (D_HID * D_IN);
    int t = idx - r * (D_HID * D_IN);
    int j = t >> 7, d = t & 127;
    W1Tb[idx] = f2bf(W1[(r * D_IN + d) * D_HID + j]);
  } else if (idx < T2) {
    int k2 = idx - T1;
    int r = k2 / (16 * D_HID);
    int t = k2 - r * (16 * D_HID);
    int n = t >> 6, k = t & 63;
    W2Tb[k2] = (n < D_OUT) ? f2bf(W2[(r * D_HID + k) * D_OUT + n]) : (u16)0;
  } else if (idx < T3) {
    int k2 = idx - T2;
    int j = k2 >> 7, d = k2 & 127;
    loop1Tb[k2] = f2bf(loop1[d * D_HID + j]);
  }
}

// ---- counting sort of edges by relation ----
__global__ void k_zero(int* __restrict__ hist){
  if (threadIdx.x < N_RELS) hist[threadIdx.x] = 0;
}

__global__ __launch_bounds__(256) void k_hist(const int* __restrict__ et, int* __restrict__ hist){
  __shared__ int lh[N_RELS];
  int tid = threadIdx.x;
  if (tid < N_RELS) lh[tid] = 0;
  __syncthreads();
  int e = blockIdx.x * 256 + tid;
  if (e < N_EDGES) atomicAdd(&lh[et[e]], 1);
  __syncthreads();
  if (tid < N_RELS && lh[tid]) atomicAdd(&hist[tid], lh[tid]);
}

__global__ void k_scan(const int* __restrict__ hist, int* __restrict__ offs,
                       int* __restrict__ toff, int* __restrict__ cursor){
  if (threadIdx.x == 0) {
    int acc = 0, tacc = 0;
    offs[0] = 0; toff[0] = 0;
    for (int r = 0; r < N_RELS; ++r) {
      cursor[r] = acc;
      int c = hist[r];
      acc += c;               offs[r + 1] = acc;
      tacc += (c + 63) >> 6;  toff[r + 1] = tacc;
    }
  }
}

__global__ __launch_bounds__(256) void k_scatter(const int* __restrict__ et,
                                                 int* __restrict__ cursor,
                                                 int* __restrict__ perm){
  __shared__ int lh[N_RELS], base[N_RELS];
  int tid = threadIdx.x;
  if (tid < N_RELS) lh[tid] = 0;
  __syncthreads();
  int e = blockIdx.x * 256 + tid;
  int r = 0, my = 0;
  bool valid = e < N_EDGES;
  if (valid) { r = et[e]; my = atomicAdd(&lh[r], 1); }
  __syncthreads();
  if (tid < N_RELS && lh[tid]) base[tid] = atomicAdd(&cursor[tid], lh[tid]);
  __syncthreads();
  if (valid) perm[base[r] + my] = e;
}

// Self-loop layer 1: agg1b[64-node tile] = bf16(feat @ loop1 + b1). Full init of agg1b.
__global__ __launch_bounds__(256) void k_selfloop1_mfma(
    const u16* __restrict__ featb, const u16* __restrict__ loop1Tb,
    const float* __restrict__ b1, u16* __restrict__ agg1b){
  __shared__ __align__(16) u16 Als[64][136];
  __shared__ __align__(16) u16 Bls[64][136];
  int tid = threadIdx.x;
  int base = blockIdx.x * 64;
  { // B tile: loop1Tb, 64 x 128 bf16 (16 KB)
    int j = tid >> 2, seg = tid & 3;
    const uint4* g = (const uint4*)(loop1Tb + j * 128) + seg * 4;
    uint4* d = (uint4*)&Bls[j][seg * 32];
    d[0] = g[0]; d[1] = g[1]; d[2] = g[2]; d[3] = g[3];
  }
  { // A tile: featb rows (bf16, straight copy)
    int i = tid >> 2, seg = tid & 3;
    int n = base + i; if (n >= N_NODES) n = N_NODES - 1;  // clamp; stores guarded below
    const uint4* g = (const uint4*)(featb + n * D_IN) + seg * 4;
    uint4* d = (uint4*)&Als[i][seg * 32];
    d[0] = g[0]; d[1] = g[1]; d[2] = g[2]; d[3] = g[3];
  }
  __syncthreads();

  int w = tid >> 6, lane = tid & 63;
  int r16 = lane & 15, c4 = lane >> 4;
  sfrag aF[4];
  #pragma unroll
  for (int kk = 0; kk < 4; ++kk)
    aF[kk] = *(const sfrag*)&Als[w * 16 + r16][kk * 32 + c4 * 8];
  #pragma unroll
  for (int ct = 0; ct < 4; ++ct) {
    f32x4 acc = {0.f, 0.f, 0.f, 0.f};
    #pragma unroll
    for (int kk = 0; kk < 4; ++kk) {
      sfrag bF = *(const sfrag*)&Bls[ct * 16 + r16][kk * 32 + c4 * 8];
      acc = __builtin_amdgcn_mfma_f32_16x16x32_bf16(aF[kk], bF, acc, 0, 0, 0);
    }
    int col = ct * 16 + r16;
    float bias = b1[col];
    #pragma unroll
    for (int reg = 0; reg < 4; ++reg) {
      int row = base + w * 16 + c4 * 4 + reg;   // D: col=lane&15, row=(lane>>4)*4+reg
      if (row < N_NODES) agg1b[row * D_HID + col] = f2bf(acc[reg] + bias);
    }
  }
}

// Layer-1 edge messages: 64 edges (one relation) x 64 cols, K=128 bf16 MFMA;
// scatter via packed bf16x2 atomics (2 cols per op).
__global__ __launch_bounds__(256) void k_edge1_mfma(
    const u16* __restrict__ featb, const u16* __restrict__ W1Tb,
    const int* __restrict__ src, const int* __restrict__ dst,
    const int* __restrict__ perm, const int* __restrict__ offs,
    const int* __restrict__ toff, u16* __restrict__ agg1b){
  __shared__ __align__(16) u16 Als[64][136];
  __shared__ __align__(16) u16 Bls[64][136];
  __shared__ int dstIds[64];
  __shared__ int sMeta[3];   // rel, tileStart, vcount
  int tid = threadIdx.x;
  if (tid == 0) {
    int b = blockIdx.x, r = 0, vc = 0, ts = 0;
    if (b < toff[N_RELS]) {
      while (b >= toff[r + 1]) ++r;
      ts = offs[r] + ((b - toff[r]) << 6);
      vc = offs[r + 1] - ts; if (vc > 64) vc = 64;
    }
    sMeta[0] = r; sMeta[1] = ts; sMeta[2] = vc;
  }
  __syncthreads();
  int vcount = sMeta[2];
  if (vcount == 0) return;                       // uniform exit
  int rel = sMeta[0], tileStart = sMeta[1];

  { // B tile: W1Tb[rel], 64 x 128 bf16 (16 KB)
    int j = tid >> 2, seg = tid & 3;
    const uint4* g = (const uint4*)(W1Tb + (rel * 64 + j) * 128) + seg * 4;
    uint4* d = (uint4*)&Bls[j][seg * 32];
    d[0] = g[0]; d[1] = g[1]; d[2] = g[2]; d[3] = g[3];
  }
  { // gather A tile: featb rows (bf16, straight copy)
    int i = tid >> 2, seg = tid & 3;
    if (i < vcount) {
      int e = perm[tileStart + i];
      if (seg == 0) dstIds[i] = dst[e];
      const uint4* g = (const uint4*)(featb + src[e] * D_IN) + seg * 4;
      uint4* d = (uint4*)&Als[i][seg * 32];
      d[0] = g[0]; d[1] = g[1]; d[2] = g[2]; d[3] = g[3];
    } else {
      if (seg == 0) dstIds[i] = -1;
      uint4 z = make_uint4(0, 0, 0, 0);
      uint4* d = (uint4*)&Als[i][seg * 32];
      d[0] = z; d[1] = z; d[2] = z; d[3] = z;
    }
  }
  __syncthreads();

  int w = tid >> 6, lane = tid & 63;
  int r16 = lane & 15, c4 = lane >> 4;
  sfrag aF[4];
  #pragma unroll
  for (int kk = 0; kk < 4; ++kk)
    aF[kk] = *(const sfrag*)&Als[w * 16 + r16][kk * 32 + c4 * 8];
  #pragma unroll
  for (int ct = 0; ct < 4; ++ct) {
    f32x4 acc = {0.f, 0.f, 0.f, 0.f};
    #pragma unroll
    for (int kk = 0; kk < 4; ++kk) {
      sfrag bF = *(const sfrag*)&Bls[ct * 16 + r16][kk * 32 + c4 * 8];
      acc = __builtin_amdgcn_mfma_f32_16x16x32_bf16(aF[kk], bF, acc, 0, 0, 0);
    }
    int col = ct * 16 + r16;                     // adjacent r16 lanes = adjacent cols
    #pragma unroll
    for (int reg = 0; reg < 4; ++reg) {
      float other = __shfl_xor(acc[reg], 1);     // partner col's value, same row
      if (!(r16 & 1)) {                          // even lane owns the pair (col, col+1)
        int row = w * 16 + c4 * 4 + reg;         // D: col=lane&15, row=(lane>>4)*4+reg
        int dn = dstIds[row];
        if (dn >= 0) {
          u32 p = (u32)f2bf(acc[reg]) | ((u32)f2bf(other) << 16);
          unsigned long long a = (unsigned long long)(agg1b + dn * D_HID + col);
          asm volatile("global_atomic_pk_add_bf16 %0, %1, off"
                       :: "v"(a), "v"(p) : "memory");
        }
      }
    }
  }
  asm volatile("s_waitcnt vmcnt(0)" ::: "memory");  // drain fire-and-forget atomics
}

// relu(agg1b) in place (exact on bf16); out[n,k] = relu row @ loop2[:,k] + b2[k] (full init)
__global__ __launch_bounds__(256) void k_relu_self2(u16* __restrict__ agg1b,
                                                     const float* __restrict__ loop2,
                                                     const float* __restrict__ b2,
                                                     float* __restrict__ out){
  int wave = threadIdx.x >> 6, lane = threadIdx.x & 63;
  int n = blockIdx.x * 4 + wave;
  u16 u = agg1b[n * D_HID + lane];
  float v = bf2f(u);
  bool neg = v <= 0.f;
  if (neg) v = 0.f;
  agg1b[n * D_HID + lane] = neg ? (u16)0 : u;   // exact relu on bf16
  float2 lw = ((const float2*)loop2)[lane];
  float p0 = v * lw.x, p1 = v * lw.y;
  for (int off = 32; off; off >>= 1) {
    p0 += __shfl_down(p0, off);
    p1 += __shfl_down(p1, off);
  }
  if (lane == 0) {
    out[n * 2]     = p0 + b2[0];
    out[n * 2 + 1] = p1 + b2[1];
  }
}

// Layer-2 edge messages: 64 edges x 16 cols (2 valid), K=64, bf16 MFMA.
__global__ __launch_bounds__(256) void k_edge2_mfma(
    const u16* __restrict__ h1b, const u16* __restrict__ W2Tb,
    const int* __restrict__ src, const int* __restrict__ dst,
    const int* __restrict__ perm, const int* __restrict__ offs,
    const int* __restrict__ toff, float* __restrict__ out){
  __shared__ __align__(16) u16 Als[64][72];
  __shared__ __align__(16) u16 Bls[16][72];
  __shared__ int dstIds[64];
  __shared__ int sMeta[3];
  int tid = threadIdx.x;
  if (tid == 0) {
    int b = blockIdx.x, r = 0, vc = 0, ts = 0;
    if (b < toff[N_RELS]) {
      while (b >= toff[r + 1]) ++r;
      ts = offs[r] + ((b - toff[r]) << 6);
      vc = offs[r + 1] - ts; if (vc > 64) vc = 64;
    }
    sMeta[0] = r; sMeta[1] = ts; sMeta[2] = vc;
  }
  __syncthreads();
  int vcount = sMeta[2];
  if (vcount == 0) return;
  int rel = sMeta[0], tileStart = sMeta[1];

  if (tid < 128) {   // B tile: 16 x 64 bf16 = 128 uint4
    int n = tid >> 3, q = tid & 7;
    ((uint4*)&Bls[n][0])[q] = ((const uint4*)(W2Tb + rel * 16 * 64))[tid];
  }
  { // gather A: h1b rows (bf16)
    int i = tid >> 2, seg = tid & 3;
    if (i < vcount) {
      int e = perm[tileStart + i];
      if (seg == 0) dstIds[i] = dst[e];
      const uint4* g = (const uint4*)(h1b + src[e] * D_HID) + seg * 2;
      *(uint4*)&Als[i][seg * 16]     = g[0];
      *(uint4*)&Als[i][seg * 16 + 8] = g[1];
    } else {
      if (seg == 0) dstIds[i] = -1;
      uint4 z = make_uint4(0, 0, 0, 0);
      *(uint4*)&Als[i][seg * 16]     = z;
      *(uint4*)&Als[i][seg * 16 + 8] = z;
    }
  }
  __syncthreads();

  int w = tid >> 6, lane = tid & 63;
  int r16 = lane & 15, c4 = lane >> 4;
  f32x4 acc = {0.f, 0.f, 0.f, 0.f};
  #pragma unroll
  for (int kk = 0; kk < 2; ++kk) {
    sfrag aF = *(const sfrag*)&Als[w * 16 + r16][kk * 32 + c4 * 8];
    sfrag bF = *(const sfrag*)&Bls[r16][kk * 32 + c4 * 8];
    acc = __builtin_amdgcn_mfma_f32_16x16x32_bf16(aF, bF, acc, 0, 0, 0);
  }
  if (r16 < D_OUT) {
    #pragma unroll
    for (int reg = 0; reg < 4; ++reg) {
      int row = w * 16 + c4 * 4 + reg;
      int dn = dstIds[row];
      if (dn >= 0) atomicAdd(&out[dn * D_OUT + r16], acc[reg]);
    }
  }
}

extern "C" void kernel_launch(void* const* d_in, const int* in_sizes, int n_in,
                              void* d_out, int out_size, void* d_ws, size_t ws_size,
                              hipStream_t stream){
  const float* feat  = (const float*)d_in[0];
  const float* W1    = (const float*)d_in[1];
  const float* loop1 = (const float*)d_in[2];
  const float* b1    = (const float*)d_in[3];
  const float* W2    = (const float*)d_in[4];
  const float* loop2 = (const float*)d_in[5];
  const float* b2    = (const float*)d_in[6];
  const int* src     = (const int*)d_in[7];
  const int* dst     = (const int*)d_in[8];
  const int* et      = (const int*)d_in[9];
  float* out = (float*)d_out;

  // workspace layout (16B-aligned), ~22 MB total
  char* w = (char*)d_ws;
  u16*   W1Tb    = (u16*)(w);                  // 311296 B
  u16*   W2Tb    = (u16*)(w + 311296);         //  38912 B
  u16*   loop1Tb = (u16*)(w + 350208);         //  16384 B
  int*   hist    = (int*)(w + 382976);
  int*   cursor  = (int*)(w + 383104);
  int*   offs    = (int*)(w + 383232);
  int*   toff    = (int*)(w + 383360);
  int*   perm    = (int*)(w + 383488);         // 2.4 MB -> end 2783488
  u16*   featb   = (u16*)(w + 2783488);        // 12.8 MB -> end 15583488
  u16*   agg1b   = (u16*)(w + 15583488);       // 6.4 MB  -> end 21983488

  const int MAX_TILES = (N_EDGES + 63) / 64 + N_RELS;   // 9394 upper bound

  k_prep          <<<716,   256, 0, stream>>>(W1, loop1, W2, W1Tb, loop1Tb, W2Tb);
  k_featb         <<<12500, 256, 0, stream>>>(feat, featb);
  k_zero          <<<1,      64, 0, stream>>>(hist);
  k_hist          <<<2344,  256, 0, stream>>>(et, hist);
  k_scan          <<<1,      64, 0, stream>>>(hist, offs, toff, cursor);
  k_scatter       <<<2344,  256, 0, stream>>>(et, cursor, perm);
  k_selfloop1_mfma<<<(N_NODES + 63) / 64, 256, 0, stream>>>(featb, loop1Tb, b1, agg1b);
  k_edge1_mfma    <<<MAX_TILES,   256, 0, stream>>>(featb, W1Tb, src, dst, perm, offs, toff, agg1b);
  k_relu_self2    <<<N_NODES / 4, 256, 0, stream>>>(agg1b, loop2, b2, out);
  k_edge2_mfma    <<<MAX_TILES,   256, 0, stream>>>(agg1b, W2Tb, src, dst, perm, offs, toff, out);
}